// Round 3
// baseline (542.874 us; speedup 1.0000x reference)
//
#include <hip/hip_runtime.h>
#include <hip/hip_bf16.h>

#define NN 100000      // nodes
#define NE 1000000     // edges
#define NPART 391      // (NN+255)/256 blocks for layer-2 partials

// ---------------- workspace layout (4-byte units) ----------------
#define OFF_COUNTS   0                        // u32[NN]   (zeroed by k0)
#define OFF_OFFSETS  (NN)                     // u32[NN+1]
#define OFF_CURSORS  (2*NN + 8)               // u32[NN]
#define OFF_CLCR     (3*NN + 8)               // f32[8]
#define OFF_PAYLOAD  (3*NN + 16)              // float4[NE]  (16B aligned)
#define OFF_BSRC     (3*NN + 16 + 4*NE)       // u32[NE]
#define OFF_Z2       (3*NN + 16 + 5*NE)       // f32[32*NN]  (16B aligned)
#define OFF_EL2      (35*NN + 16 + 5*NE)      // f32[NN]
#define OFF_ER2      (36*NN + 16 + 5*NE)      // f32[NN]
#define OFF_PARTS    (37*NN + 16 + 5*NE)      // f32[NPART*32]

// zero hist counts + compute cl[k]=W1[k,:64]@al1, cr[k]=W1[k,:64]@ar1
__global__ void k0_prep(unsigned* __restrict__ counts, const float* __restrict__ W1,
                        const float* __restrict__ al1, const float* __restrict__ ar1,
                        float* __restrict__ clcr) {
    int i = blockIdx.x * blockDim.x + threadIdx.x;
    if (i < NN) counts[i] = 0u;
    if (blockIdx.x == 0 && threadIdx.x < 64) {
        int j = threadIdx.x;
        float a = al1[j], r = ar1[j];
#pragma unroll
        for (int k = 0; k < 3; ++k) {
            float wv = W1[k*128 + j];
            float vl = wv * a, vr = wv * r;
            for (int off = 32; off > 0; off >>= 1) {
                vl += __shfl_down(vl, off);
                vr += __shfl_down(vr, off);
            }
            if (j == 0) { clcr[k] = vl; clcr[4 + k] = vr; }
        }
    }
}

// histogram of dst
__global__ void k1_hist(const int* __restrict__ dst, unsigned* __restrict__ counts) {
    int e = blockIdx.x * blockDim.x + threadIdx.x;
    if (e < NE) atomicAdd(counts + dst[e], 1u);
}

// single-block exclusive scan of counts -> offsets[NN+1], cursors copy
__global__ void k2_scan(const unsigned* __restrict__ counts, unsigned* __restrict__ offsets,
                        unsigned* __restrict__ cursors) {
    const int PER = 98;  // 1024*98 >= NN
    int t = threadIdx.x;
    int beg = t * PER, end = min(beg + PER, NN);
    unsigned s = 0;
    for (int i = beg; i < end; ++i) s += counts[i];
    // inclusive scan within wave
    unsigned v = s;
    int lane = t & 63;
    for (int off = 1; off < 64; off <<= 1) {
        unsigned u = __shfl_up(v, off);
        if (lane >= off) v += u;
    }
    __shared__ unsigned wsum[16], wexc[16];
    int wv = t >> 6;
    if (lane == 63) wsum[wv] = v;
    __syncthreads();
    if (t == 0) {
        unsigned run = 0;
        for (int w = 0; w < 16; ++w) { wexc[w] = run; run += wsum[w]; }
    }
    __syncthreads();
    unsigned run = wexc[wv] + (v - s);   // exclusive offset for this thread's range
    for (int i = beg; i < end; ++i) {
        offsets[i] = run;
        cursors[i] = run;
        run += counts[i];
    }
    if (t == 1023) offsets[NN] = run;    // == NE
}

// per edge: p = exp(leaky(feat[s]·cl + feat[d]·cr)); scatter payload+src to CSR slot
__global__ void k3_scatter(const int* __restrict__ src, const int* __restrict__ dst,
                           const float* __restrict__ feat, const float* __restrict__ clcr,
                           unsigned* __restrict__ cursors, float4* __restrict__ payload,
                           unsigned* __restrict__ bsrc) {
    int e = blockIdx.x * blockDim.x + threadIdx.x;
    if (e >= NE) return;
    int s = src[e], d = dst[e];
    float fs0 = feat[s*3], fs1 = feat[s*3+1], fs2 = feat[s*3+2];
    float fd0 = feat[d*3], fd1 = feat[d*3+1], fd2 = feat[d*3+2];
    float ee = fs0*clcr[0] + fs1*clcr[1] + fs2*clcr[2]
             + fd0*clcr[4] + fd1*clcr[5] + fd2*clcr[6];
    ee = (ee >= 0.f) ? ee : 0.2f * ee;
    float p = __expf(ee);
    unsigned pos = atomicAdd(cursors + d, 1u);
    payload[pos] = make_float4(p*fs0, p*fs1, p*fs2, p);
    bsrc[pos] = (unsigned)s;
}

// per node: gather CSR payload (coalesced, no atomics) -> r1 -> z2 row, el2, er2
__global__ void k4_node(const unsigned* __restrict__ offsets, const float4* __restrict__ payload,
                        const float* __restrict__ W1, const float* __restrict__ b1,
                        const float* __restrict__ W2, const float* __restrict__ al2,
                        const float* __restrict__ ar2,
                        float* __restrict__ z2, float* __restrict__ el2, float* __restrict__ er2) {
    __shared__ float sW1[192], sb1[64], sW2[1920], sal2[30], sar2[30];
    int tid = threadIdx.x;
    for (int i = tid; i < 192; i += 256) sW1[i] = W1[(i >> 6)*128 + (i & 63)];
    for (int i = tid; i < 1920; i += 256) sW2[i] = W2[(i / 30)*60 + (i % 30)];
    if (tid < 64) sb1[tid] = b1[tid];
    if (tid < 30) { sal2[tid] = al2[tid]; sar2[tid] = ar2[tid]; }
    __syncthreads();
    int n = blockIdx.x * 256 + tid;
    if (n >= NN) return;
    unsigned beg = offsets[n], end = offsets[n + 1];
    float4 sm = make_float4(0.f, 0.f, 0.f, 0.f);
    for (unsigned i = beg; i < end; ++i) {
        float4 v = payload[i];
        sm.x += v.x; sm.y += v.y; sm.z += v.z; sm.w += v.w;
    }
    float inv = (sm.w > 0.f) ? 1.f / sm.w : 0.f;
    float a0 = sm.x * inv, a1 = sm.y * inv, a2 = sm.z * inv;
    float r[64];
#pragma unroll
    for (int j = 0; j < 64; ++j)
        r[j] = fmaxf(a0*sW1[j] + a1*sW1[64 + j] + a2*sW1[128 + j] + sb1[j], 0.f);
    float sl = 0.f, sr = 0.f;
    for (int c = 0; c < 30; ++c) {
        float z = 0.f;
#pragma unroll
        for (int j = 0; j < 64; ++j) z += r[j] * sW2[j*30 + c];
        z2[(size_t)n*32 + c] = z;
        sl += z * sal2[c];
        sr += z * sar2[c];
    }
    z2[(size_t)n*32 + 30] = 0.f;
    z2[(size_t)n*32 + 31] = 0.f;
    el2[n] = sl;
    er2[n] = sr;
}

// per node: gather layer-2 in-edges, den2 + weighted sum in one pass, block colsum partials
__global__ void k5_layer2(const unsigned* __restrict__ offsets, const unsigned* __restrict__ bsrc,
                          const float* __restrict__ el2, const float* __restrict__ er2,
                          const float* __restrict__ z2, float* __restrict__ part) {
    int tid = threadIdx.x;
    int lane = tid & 63, wv = tid >> 6;
    int n = blockIdx.x * 256 + tid;
    float acc[32];
#pragma unroll
    for (int q = 0; q < 32; ++q) acc[q] = 0.f;
    if (n < NN) {
        unsigned beg = offsets[n], end = offsets[n + 1];
        float erd = er2[n];
        float sp = 0.f;
        for (unsigned i = beg; i < end; ++i) {
            unsigned s = bsrc[i];
            float ee = el2[s] + erd;
            ee = (ee >= 0.f) ? ee : 0.2f * ee;
            float p = __expf(ee);
            sp += p;
            const float4* zr = (const float4*)(z2 + (size_t)s * 32);
#pragma unroll
            for (int q = 0; q < 8; ++q) {
                float4 v = zr[q];
                acc[4*q + 0] += p * v.x;
                acc[4*q + 1] += p * v.y;
                acc[4*q + 2] += p * v.z;
                acc[4*q + 3] += p * v.w;
            }
        }
        float inv = (sp > 0.f) ? 1.f / sp : 0.f;
#pragma unroll
        for (int q = 0; q < 32; ++q) acc[q] *= inv;
    }
#pragma unroll
    for (int q = 0; q < 32; ++q)
        for (int off = 32; off > 0; off >>= 1) acc[q] += __shfl_down(acc[q], off);
    __shared__ float sh[4][32];
    if (lane == 0) {
#pragma unroll
        for (int q = 0; q < 32; ++q) sh[wv][q] = acc[q];
    }
    __syncthreads();
    if (tid < 32)
        part[blockIdx.x * 32 + tid] = sh[0][tid] + sh[1][tid] + sh[2][tid] + sh[3][tid];
}

// single block: image path, sum partials, a00 = colsum/N + b2[0], concat, log_softmax
__global__ void k6_final(const float* __restrict__ x, const float* __restrict__ vocab,
                         const float* __restrict__ W_lin1, const float* __restrict__ w2,
                         const float* __restrict__ w3, const float* __restrict__ W4,
                         const float* __restrict__ b2, const float* __restrict__ part,
                         float* __restrict__ out) {
    __shared__ float sh[256];
    __shared__ float hvec[70];
    int tid = threadIdx.x;
    int r = tid >> 3, sub = tid & 7;
    float pt = 0.f;
    if (r < 30) {
        for (int k = sub; k < 512; k += 8) pt += W_lin1[r*512 + k] * x[k];
    }
    sh[tid] = pt;
    __syncthreads();
    if (tid < 30) {
        float hi = 0.f;
        for (int i = 0; i < 8; ++i) hi += sh[tid*8 + i];
        float acc = 0.f;
        for (int k = 0; k < 64; ++k) acc += w3[k] / (1.f + __expf(-w2[k] * hi));
        hvec[30 + tid] = 1.f / (1.f + __expf(-acc));
        float cs = 0.f;
        for (int b = 0; b < NPART; ++b) cs += part[b*32 + tid];
        hvec[tid] = cs * (1.0f / (float)NN) + b2[tid];
    }
    if (tid >= 64 && tid < 74) hvec[60 + (tid - 64)] = vocab[tid - 64];
    __syncthreads();
    if (tid == 0) {
        float p0 = 0.f, p1 = 0.f;
        for (int k = 0; k < 70; ++k) {
            p0 += W4[k] * hvec[k];
            p1 += W4[70 + k] * hvec[k];
        }
        float mx = fmaxf(p0, p1);
        float l = logf(__expf(p0 - mx) + __expf(p1 - mx));
        out[0] = p0 - mx - l;
        out[1] = p1 - mx - l;
    }
}

extern "C" void kernel_launch(void* const* d_in, const int* in_sizes, int n_in,
                              void* d_out, int out_size, void* d_ws, size_t ws_size,
                              hipStream_t stream) {
    const float* x      = (const float*)d_in[0];
    const float* feat   = (const float*)d_in[1];
    const float* vocab  = (const float*)d_in[2];
    const int*   src    = (const int*)d_in[3];
    const int*   dst    = (const int*)d_in[4];
    const float* W_lin1 = (const float*)d_in[5];
    const float* w_c2   = (const float*)d_in[6];
    const float* w_c3   = (const float*)d_in[7];
    const float* W_lin4 = (const float*)d_in[8];
    const float* W1     = (const float*)d_in[9];
    const float* al1    = (const float*)d_in[10];
    const float* ar1    = (const float*)d_in[11];
    const float* b1     = (const float*)d_in[12];
    const float* W2     = (const float*)d_in[13];
    const float* al2    = (const float*)d_in[14];
    const float* ar2    = (const float*)d_in[15];
    const float* b2     = (const float*)d_in[16];
    float* out = (float*)d_out;
    float* w = (float*)d_ws;

    unsigned* counts  = (unsigned*)(w + OFF_COUNTS);
    unsigned* offsets = (unsigned*)(w + OFF_OFFSETS);
    unsigned* cursors = (unsigned*)(w + OFF_CURSORS);
    float*    clcr    = w + OFF_CLCR;
    float4*   payload = (float4*)(w + OFF_PAYLOAD);
    unsigned* bsrc    = (unsigned*)(w + OFF_BSRC);
    float*    z2      = w + OFF_Z2;
    float*    el2     = w + OFF_EL2;
    float*    er2     = w + OFF_ER2;
    float*    part    = w + OFF_PARTS;

    k0_prep<<<(NN + 255) / 256, 256, 0, stream>>>(counts, W1, al1, ar1, clcr);
    k1_hist<<<(NE + 255) / 256, 256, 0, stream>>>(dst, counts);
    k2_scan<<<1, 1024, 0, stream>>>(counts, offsets, cursors);
    k3_scatter<<<(NE + 255) / 256, 256, 0, stream>>>(src, dst, feat, clcr, cursors, payload, bsrc);
    k4_node<<<(NN + 255) / 256, 256, 0, stream>>>(offsets, payload, W1, b1, W2, al2, ar2, z2, el2, er2);
    k5_layer2<<<NPART, 256, 0, stream>>>(offsets, bsrc, el2, er2, z2, part);
    k6_final<<<1, 256, 0, stream>>>(x, vocab, W_lin1, w_c2, w_c3, W_lin4, b2, part, out);
}

// Round 4
// 291.435 us; speedup vs baseline: 1.8628x; 1.8628x over previous
//
#include <hip/hip_runtime.h>
#include <hip/hip_bf16.h>

#define NN 100000      // nodes
#define NE 1000000     // edges
#define NPART 391      // ceil(NN/256)

// ---------------- workspace layout (4-byte units) ----------------
#define OFF_COUNTS   0              // u32[NN]   (zeroed by k0)
#define OFF_OFFSETS  100000         // u32[NN+1]
#define OFF_BSUM     200004         // u32[NPART]
#define OFF_BOFF     200396         // u32[NPART]
#define OFF_CLCR     200788         // f32[8]
#define OFF_RANK     200796         // u32[NE]
#define OFF_PAYLOAD  1200796        // float4[NE]  (16B aligned: /4 ok)
#define OFF_BSRC     5200796        // u32[NE]
#define OFF_Z2       6200796        // f32[32*NN]  (16B aligned)
#define OFF_EL2      9400796        // f32[NN]
#define OFF_ER2      9500796        // f32[NN]
#define OFF_PARTS    9600796        // f32[NPART*32]

// zero hist counts + compute cl[k]=W1[k,:64]@al1, cr[k]=W1[k,:64]@ar1
__global__ void k0_prep(unsigned* __restrict__ counts, const float* __restrict__ W1,
                        const float* __restrict__ al1, const float* __restrict__ ar1,
                        float* __restrict__ clcr) {
    int i = blockIdx.x * blockDim.x + threadIdx.x;
    if (i < NN) counts[i] = 0u;
    if (blockIdx.x == 0 && threadIdx.x < 64) {
        int j = threadIdx.x;
        float a = al1[j], r = ar1[j];
#pragma unroll
        for (int k = 0; k < 3; ++k) {
            float wv = W1[k*128 + j];
            float vl = wv * a, vr = wv * r;
            for (int off = 32; off > 0; off >>= 1) {
                vl += __shfl_down(vl, off);
                vr += __shfl_down(vr, off);
            }
            if (j == 0) { clcr[k] = vl; clcr[4 + k] = vr; }
        }
    }
}

// histogram of dst; returned old count = stable per-node rank for this edge
__global__ void k1_hist(const int* __restrict__ dst, unsigned* __restrict__ counts,
                        unsigned* __restrict__ rank) {
    int e = blockIdx.x * blockDim.x + threadIdx.x;
    if (e < NE) rank[e] = atomicAdd(counts + dst[e], 1u);
}

// scan phase 1: per-block sum of counts
__global__ void kS1(const unsigned* __restrict__ counts, unsigned* __restrict__ bsum) {
    __shared__ unsigned sh[256];
    int t = threadIdx.x;
    int i = blockIdx.x * 256 + t;
    sh[t] = (i < NN) ? counts[i] : 0u;
    __syncthreads();
    for (int off = 128; off > 0; off >>= 1) {
        if (t < off) sh[t] += sh[t + off];
        __syncthreads();
    }
    if (t == 0) bsum[blockIdx.x] = sh[0];
}

// scan phase 2: single-block exclusive scan of the NPART block sums
__global__ void kS2(const unsigned* __restrict__ bsum, unsigned* __restrict__ boff) {
    __shared__ unsigned sh[512];
    int t = threadIdx.x;
    unsigned v = (t < NPART) ? bsum[t] : 0u;
    sh[t] = v;
    __syncthreads();
    for (int off = 1; off < 512; off <<= 1) {
        unsigned u = (t >= off) ? sh[t - off] : 0u;
        __syncthreads();
        sh[t] += u;
        __syncthreads();
    }
    if (t < NPART) boff[t] = sh[t] - v;   // exclusive
}

// scan phase 3: intra-block exclusive scan + block offset -> offsets[]
__global__ void kS3(const unsigned* __restrict__ counts, const unsigned* __restrict__ boff,
                    unsigned* __restrict__ offsets) {
    __shared__ unsigned sh[256];
    int t = threadIdx.x;
    int i = blockIdx.x * 256 + t;
    unsigned v = (i < NN) ? counts[i] : 0u;
    sh[t] = v;
    __syncthreads();
    for (int off = 1; off < 256; off <<= 1) {
        unsigned u = (t >= off) ? sh[t - off] : 0u;
        __syncthreads();
        sh[t] += u;
        __syncthreads();
    }
    if (i < NN) offsets[i] = boff[blockIdx.x] + sh[t] - v;
    if (i == NN - 1) offsets[NN] = NE;
}

// per edge: p = exp(leaky(feat[s]·cl + feat[d]·cr)); slot = offsets[d]+rank[e] (no atomics)
__global__ void k3_scatter(const int* __restrict__ src, const int* __restrict__ dst,
                           const float* __restrict__ feat, const float* __restrict__ clcr,
                           const unsigned* __restrict__ offsets, const unsigned* __restrict__ rank,
                           float4* __restrict__ payload, unsigned* __restrict__ bsrc) {
    int e = blockIdx.x * blockDim.x + threadIdx.x;
    if (e >= NE) return;
    int s = src[e], d = dst[e];
    float fs0 = feat[s*3], fs1 = feat[s*3+1], fs2 = feat[s*3+2];
    float fd0 = feat[d*3], fd1 = feat[d*3+1], fd2 = feat[d*3+2];
    float ee = fs0*clcr[0] + fs1*clcr[1] + fs2*clcr[2]
             + fd0*clcr[4] + fd1*clcr[5] + fd2*clcr[6];
    ee = (ee >= 0.f) ? ee : 0.2f * ee;
    float p = __expf(ee);
    unsigned pos = offsets[d] + rank[e];
    payload[pos] = make_float4(p*fs0, p*fs1, p*fs2, p);
    bsrc[pos] = (unsigned)s;
}

// per node: gather CSR payload (no atomics) -> r1 -> z2 row, el2, er2
__global__ void k4_node(const unsigned* __restrict__ offsets, const float4* __restrict__ payload,
                        const float* __restrict__ W1, const float* __restrict__ b1,
                        const float* __restrict__ W2, const float* __restrict__ al2,
                        const float* __restrict__ ar2,
                        float* __restrict__ z2, float* __restrict__ el2, float* __restrict__ er2) {
    __shared__ float sW1[192], sb1[64], sW2[1920], sal2[30], sar2[30];
    int tid = threadIdx.x;
    for (int i = tid; i < 192; i += 256) sW1[i] = W1[(i >> 6)*128 + (i & 63)];
    for (int i = tid; i < 1920; i += 256) sW2[i] = W2[(i / 30)*60 + (i % 30)];
    if (tid < 64) sb1[tid] = b1[tid];
    if (tid < 30) { sal2[tid] = al2[tid]; sar2[tid] = ar2[tid]; }
    __syncthreads();
    int n = blockIdx.x * 256 + tid;
    if (n >= NN) return;
    unsigned beg = offsets[n], end = offsets[n + 1];
    float4 sm = make_float4(0.f, 0.f, 0.f, 0.f);
    for (unsigned i = beg; i < end; ++i) {
        float4 v = payload[i];
        sm.x += v.x; sm.y += v.y; sm.z += v.z; sm.w += v.w;
    }
    float inv = (sm.w > 0.f) ? 1.f / sm.w : 0.f;
    float a0 = sm.x * inv, a1 = sm.y * inv, a2 = sm.z * inv;
    float r[64];
#pragma unroll
    for (int j = 0; j < 64; ++j)
        r[j] = fmaxf(a0*sW1[j] + a1*sW1[64 + j] + a2*sW1[128 + j] + sb1[j], 0.f);
    float sl = 0.f, sr = 0.f;
    for (int c = 0; c < 30; ++c) {
        float z = 0.f;
#pragma unroll
        for (int j = 0; j < 64; ++j) z += r[j] * sW2[j*30 + c];
        z2[(size_t)n*32 + c] = z;
        sl += z * sal2[c];
        sr += z * sar2[c];
    }
    z2[(size_t)n*32 + 30] = 0.f;
    z2[(size_t)n*32 + 31] = 0.f;
    el2[n] = sl;
    er2[n] = sr;
}

// per node: gather layer-2 in-edges, den2 + weighted sum in one pass, block colsum partials
__global__ void k5_layer2(const unsigned* __restrict__ offsets, const unsigned* __restrict__ bsrc,
                          const float* __restrict__ el2, const float* __restrict__ er2,
                          const float* __restrict__ z2, float* __restrict__ part) {
    int tid = threadIdx.x;
    int lane = tid & 63, wv = tid >> 6;
    int n = blockIdx.x * 256 + tid;
    float acc[32];
#pragma unroll
    for (int q = 0; q < 32; ++q) acc[q] = 0.f;
    if (n < NN) {
        unsigned beg = offsets[n], end = offsets[n + 1];
        float erd = er2[n];
        float sp = 0.f;
        for (unsigned i = beg; i < end; ++i) {
            unsigned s = bsrc[i];
            float ee = el2[s] + erd;
            ee = (ee >= 0.f) ? ee : 0.2f * ee;
            float p = __expf(ee);
            sp += p;
            const float4* zr = (const float4*)(z2 + (size_t)s * 32);
#pragma unroll
            for (int q = 0; q < 8; ++q) {
                float4 v = zr[q];
                acc[4*q + 0] += p * v.x;
                acc[4*q + 1] += p * v.y;
                acc[4*q + 2] += p * v.z;
                acc[4*q + 3] += p * v.w;
            }
        }
        float inv = (sp > 0.f) ? 1.f / sp : 0.f;
#pragma unroll
        for (int q = 0; q < 32; ++q) acc[q] *= inv;
    }
#pragma unroll
    for (int q = 0; q < 32; ++q)
        for (int off = 32; off > 0; off >>= 1) acc[q] += __shfl_down(acc[q], off);
    __shared__ float sh[4][32];
    if (lane == 0) {
#pragma unroll
        for (int q = 0; q < 32; ++q) sh[wv][q] = acc[q];
    }
    __syncthreads();
    if (tid < 32)
        part[blockIdx.x * 32 + tid] = sh[0][tid] + sh[1][tid] + sh[2][tid] + sh[3][tid];
}

// single block: image path, sum partials, a00 = colsum/N + b2[0], concat, log_softmax
__global__ void k6_final(const float* __restrict__ x, const float* __restrict__ vocab,
                         const float* __restrict__ W_lin1, const float* __restrict__ w2,
                         const float* __restrict__ w3, const float* __restrict__ W4,
                         const float* __restrict__ b2, const float* __restrict__ part,
                         float* __restrict__ out) {
    __shared__ float sh[256];
    __shared__ float hvec[70];
    int tid = threadIdx.x;
    int r = tid >> 3, sub = tid & 7;
    float pt = 0.f;
    if (r < 30) {
        for (int k = sub; k < 512; k += 8) pt += W_lin1[r*512 + k] * x[k];
    }
    sh[tid] = pt;
    __syncthreads();
    if (tid < 30) {
        float hi = 0.f;
        for (int i = 0; i < 8; ++i) hi += sh[tid*8 + i];
        float acc = 0.f;
        for (int k = 0; k < 64; ++k) acc += w3[k] / (1.f + __expf(-w2[k] * hi));
        hvec[30 + tid] = 1.f / (1.f + __expf(-acc));
        float cs = 0.f;
        for (int b = 0; b < NPART; ++b) cs += part[b*32 + tid];
        hvec[tid] = cs * (1.0f / (float)NN) + b2[tid];
    }
    if (tid >= 64 && tid < 74) hvec[60 + (tid - 64)] = vocab[tid - 64];
    __syncthreads();
    if (tid == 0) {
        float p0 = 0.f, p1 = 0.f;
        for (int k = 0; k < 70; ++k) {
            p0 += W4[k] * hvec[k];
            p1 += W4[70 + k] * hvec[k];
        }
        float mx = fmaxf(p0, p1);
        float l = logf(__expf(p0 - mx) + __expf(p1 - mx));
        out[0] = p0 - mx - l;
        out[1] = p1 - mx - l;
    }
}

extern "C" void kernel_launch(void* const* d_in, const int* in_sizes, int n_in,
                              void* d_out, int out_size, void* d_ws, size_t ws_size,
                              hipStream_t stream) {
    const float* x      = (const float*)d_in[0];
    const float* feat   = (const float*)d_in[1];
    const float* vocab  = (const float*)d_in[2];
    const int*   src    = (const int*)d_in[3];
    const int*   dst    = (const int*)d_in[4];
    const float* W_lin1 = (const float*)d_in[5];
    const float* w_c2   = (const float*)d_in[6];
    const float* w_c3   = (const float*)d_in[7];
    const float* W_lin4 = (const float*)d_in[8];
    const float* W1     = (const float*)d_in[9];
    const float* al1    = (const float*)d_in[10];
    const float* ar1    = (const float*)d_in[11];
    const float* b1     = (const float*)d_in[12];
    const float* W2     = (const float*)d_in[13];
    const float* al2    = (const float*)d_in[14];
    const float* ar2    = (const float*)d_in[15];
    const float* b2     = (const float*)d_in[16];
    float* out = (float*)d_out;
    float* w = (float*)d_ws;

    unsigned* counts  = (unsigned*)(w + OFF_COUNTS);
    unsigned* offsets = (unsigned*)(w + OFF_OFFSETS);
    unsigned* bsum    = (unsigned*)(w + OFF_BSUM);
    unsigned* boff    = (unsigned*)(w + OFF_BOFF);
    float*    clcr    = w + OFF_CLCR;
    unsigned* rank    = (unsigned*)(w + OFF_RANK);
    float4*   payload = (float4*)(w + OFF_PAYLOAD);
    unsigned* bsrc    = (unsigned*)(w + OFF_BSRC);
    float*    z2      = w + OFF_Z2;
    float*    el2     = w + OFF_EL2;
    float*    er2     = w + OFF_ER2;
    float*    part    = w + OFF_PARTS;

    k0_prep<<<NPART, 256, 0, stream>>>(counts, W1, al1, ar1, clcr);
    k1_hist<<<(NE + 255) / 256, 256, 0, stream>>>(dst, counts, rank);
    kS1<<<NPART, 256, 0, stream>>>(counts, bsum);
    kS2<<<1, 512, 0, stream>>>(bsum, boff);
    kS3<<<NPART, 256, 0, stream>>>(counts, boff, offsets);
    k3_scatter<<<(NE + 255) / 256, 256, 0, stream>>>(src, dst, feat, clcr, offsets, rank, payload, bsrc);
    k4_node<<<NPART, 256, 0, stream>>>(offsets, payload, W1, b1, W2, al2, ar2, z2, el2, er2);
    k5_layer2<<<NPART, 256, 0, stream>>>(offsets, bsrc, el2, er2, z2, part);
    k6_final<<<1, 256, 0, stream>>>(x, vocab, W_lin1, w_c2, w_c3, W_lin4, b2, part, out);
}

// Round 5
// 253.806 us; speedup vs baseline: 2.1389x; 1.1483x over previous
//
#include <hip/hip_runtime.h>
#include <hip/hip_bf16.h>
#include <hip/hip_fp16.h>

#define NN 100000      // nodes
#define NE 1000000     // edges
#define NPART 391      // ceil(NN/256)

// ---------------- workspace layout (4-byte units) ----------------
#define OFF_COUNTS   0              // u32[NN]   (zeroed by k0)
#define OFF_OFFSETS  100000         // u32[NN+1]
#define OFF_BSUM     200004         // u32[NPART]
#define OFF_BOFF     200396         // u32[NPART]
#define OFF_CLCR     200788         // f32[8]
#define OFF_ER1      200796         // f32[NN]
#define OFF_ER2      300796         // f32[NN]
#define OFF_RANK     400796         // u32[NE]
#define OFF_PFEAT    1400796        // float4[NN]  {f0,f1,f2,el1}  (16B aligned)
#define OFF_BSRC     1800796        // u32[NE]
#define OFF_Z2H      2800796        // half[32*NN] (64B rows; [30]=el2, [31]=0)
#define OFF_PARTS    4400796        // f32[NPART*32]

// zero hist counts + compute cl[k]=W1[k,:64]@al1, cr[k]=W1[k,:64]@ar1
__global__ void k0_prep(unsigned* __restrict__ counts, const float* __restrict__ W1,
                        const float* __restrict__ al1, const float* __restrict__ ar1,
                        float* __restrict__ clcr) {
    int i = blockIdx.x * blockDim.x + threadIdx.x;
    if (i < NN) counts[i] = 0u;
    if (blockIdx.x == 0 && threadIdx.x < 64) {
        int j = threadIdx.x;
        float a = al1[j], r = ar1[j];
#pragma unroll
        for (int k = 0; k < 3; ++k) {
            float wv = W1[k*128 + j];
            float vl = wv * a, vr = wv * r;
            for (int off = 32; off > 0; off >>= 1) {
                vl += __shfl_down(vl, off);
                vr += __shfl_down(vr, off);
            }
            if (j == 0) { clcr[k] = vl; clcr[4 + k] = vr; }
        }
    }
}

// histogram of dst (rank = stable per-node slot); low blocks also pack pfeat/er1
__global__ void k1_hist_pack(const int* __restrict__ dst, unsigned* __restrict__ counts,
                             unsigned* __restrict__ rank, const float* __restrict__ feat,
                             const float* __restrict__ clcr, float4* __restrict__ pfeat,
                             float* __restrict__ er1) {
    int e = blockIdx.x * blockDim.x + threadIdx.x;
    if (e < NE) rank[e] = atomicAdd(counts + dst[e], 1u);
    int n = e;   // same global index; blocks < NPART cover all nodes
    if (n < NN) {
        float f0 = feat[n*3], f1 = feat[n*3+1], f2 = feat[n*3+2];
        float el = f0*clcr[0] + f1*clcr[1] + f2*clcr[2];
        float er = f0*clcr[4] + f1*clcr[5] + f2*clcr[6];
        pfeat[n] = make_float4(f0, f1, f2, el);
        er1[n] = er;
    }
}

// scan phase 1: per-block sum of counts
__global__ void kS1(const unsigned* __restrict__ counts, unsigned* __restrict__ bsum) {
    __shared__ unsigned sh[256];
    int t = threadIdx.x;
    int i = blockIdx.x * 256 + t;
    sh[t] = (i < NN) ? counts[i] : 0u;
    __syncthreads();
    for (int off = 128; off > 0; off >>= 1) {
        if (t < off) sh[t] += sh[t + off];
        __syncthreads();
    }
    if (t == 0) bsum[blockIdx.x] = sh[0];
}

// scan phase 2: single-block exclusive scan of the NPART block sums
__global__ void kS2(const unsigned* __restrict__ bsum, unsigned* __restrict__ boff) {
    __shared__ unsigned sh[512];
    int t = threadIdx.x;
    unsigned v = (t < NPART) ? bsum[t] : 0u;
    sh[t] = v;
    __syncthreads();
    for (int off = 1; off < 512; off <<= 1) {
        unsigned u = (t >= off) ? sh[t - off] : 0u;
        __syncthreads();
        sh[t] += u;
        __syncthreads();
    }
    if (t < NPART) boff[t] = sh[t] - v;   // exclusive
}

// scan phase 3: intra-block exclusive scan + block offset -> offsets[]
__global__ void kS3(const unsigned* __restrict__ counts, const unsigned* __restrict__ boff,
                    unsigned* __restrict__ offsets) {
    __shared__ unsigned sh[256];
    int t = threadIdx.x;
    int i = blockIdx.x * 256 + t;
    unsigned v = (i < NN) ? counts[i] : 0u;
    sh[t] = v;
    __syncthreads();
    for (int off = 1; off < 256; off <<= 1) {
        unsigned u = (t >= off) ? sh[t - off] : 0u;
        __syncthreads();
        sh[t] += u;
        __syncthreads();
    }
    if (i < NN) offsets[i] = boff[blockIdx.x] + sh[t] - v;
    if (i == NN - 1) offsets[NN] = NE;
}

// per edge: slot = offsets[d] + rank[e]; write only the src index (4 B scatter)
__global__ void k3_scatter(const int* __restrict__ src, const int* __restrict__ dst,
                           const unsigned* __restrict__ offsets, const unsigned* __restrict__ rank,
                           unsigned* __restrict__ bsrc) {
    int e = blockIdx.x * blockDim.x + threadIdx.x;
    if (e >= NE) return;
    bsrc[offsets[dst[e]] + rank[e]] = (unsigned)src[e];
}

// per node: gather pfeat[src] (16B, L2-resident), recompute p, aggregate,
// then r1 -> z2 row (fp16, el2 packed at [30]) + er2
__global__ void k4_node(const unsigned* __restrict__ offsets, const unsigned* __restrict__ bsrc,
                        const float4* __restrict__ pfeat, const float* __restrict__ er1,
                        const float* __restrict__ W1, const float* __restrict__ b1,
                        const float* __restrict__ W2, const float* __restrict__ al2,
                        const float* __restrict__ ar2,
                        __half* __restrict__ z2h, float* __restrict__ er2) {
    __shared__ float sW1[192], sb1[64], sW2[1920], sal2[30], sar2[30];
    int tid = threadIdx.x;
    for (int i = tid; i < 192; i += 256) sW1[i] = W1[(i >> 6)*128 + (i & 63)];
    for (int i = tid; i < 1920; i += 256) sW2[i] = W2[(i / 30)*60 + (i % 30)];
    if (tid < 64) sb1[tid] = b1[tid];
    if (tid < 30) { sal2[tid] = al2[tid]; sar2[tid] = ar2[tid]; }
    __syncthreads();
    int n = blockIdx.x * 256 + tid;
    if (n >= NN) return;
    unsigned beg = offsets[n], end = offsets[n + 1];
    float erd = er1[n];
    float s0 = 0.f, s1 = 0.f, s2 = 0.f, sp = 0.f;
    for (unsigned i = beg; i < end; ++i) {
        unsigned s = bsrc[i];
        float4 v = pfeat[s];
        float ee = v.w + erd;
        ee = (ee >= 0.f) ? ee : 0.2f * ee;
        float p = __expf(ee);
        s0 += p * v.x; s1 += p * v.y; s2 += p * v.z; sp += p;
    }
    float inv = (sp > 0.f) ? 1.f / sp : 0.f;
    float a0 = s0 * inv, a1 = s1 * inv, a2 = s2 * inv;
    float r[64];
#pragma unroll
    for (int j = 0; j < 64; ++j)
        r[j] = fmaxf(a0*sW1[j] + a1*sW1[64 + j] + a2*sW1[128 + j] + sb1[j], 0.f);
    __half hrow[32];
    float sl = 0.f, sr = 0.f;
    for (int c = 0; c < 30; ++c) {
        float z = 0.f;
#pragma unroll
        for (int j = 0; j < 64; ++j) z += r[j] * sW2[j*30 + c];
        hrow[c] = __float2half(z);
        sl += z * sal2[c];
        sr += z * sar2[c];
    }
    hrow[30] = __float2half(sl);   // el2 packed into the row
    hrow[31] = __float2half(0.f);
    float4* outp = (float4*)(z2h + (size_t)n * 32);
    const float4* hp = (const float4*)hrow;
    outp[0] = hp[0]; outp[1] = hp[1]; outp[2] = hp[2]; outp[3] = hp[3];
    er2[n] = sr;
}

// per node: gather fp16 z2 rows (64 B, el2 included), softmax-weighted colsum partials
__global__ void k5_layer2(const unsigned* __restrict__ offsets, const unsigned* __restrict__ bsrc,
                          const __half* __restrict__ z2h, const float* __restrict__ er2,
                          float* __restrict__ part) {
    int tid = threadIdx.x;
    int lane = tid & 63, wv = tid >> 6;
    int n = blockIdx.x * 256 + tid;
    float acc[32];
#pragma unroll
    for (int q = 0; q < 32; ++q) acc[q] = 0.f;
    if (n < NN) {
        unsigned beg = offsets[n], end = offsets[n + 1];
        float erd = er2[n];
        float sp = 0.f;
        for (unsigned i = beg; i < end; ++i) {
            unsigned s = bsrc[i];
            const float4* zr = (const float4*)(z2h + (size_t)s * 32);
            float4 raw[4];
            raw[0] = zr[0]; raw[1] = zr[1]; raw[2] = zr[2]; raw[3] = zr[3];
            const __half2* h2 = (const __half2*)raw;
            float ee = __half2float(__low2half(h2[15])) + erd;  // el2 at element 30
            ee = (ee >= 0.f) ? ee : 0.2f * ee;
            float p = __expf(ee);
            sp += p;
#pragma unroll
            for (int q = 0; q < 16; ++q) {
                float2 f = __half22float2(h2[q]);
                acc[2*q + 0] += p * f.x;
                acc[2*q + 1] += p * f.y;
            }
        }
        float inv = (sp > 0.f) ? 1.f / sp : 0.f;
#pragma unroll
        for (int q = 0; q < 32; ++q) acc[q] *= inv;
    }
#pragma unroll
    for (int q = 0; q < 32; ++q)
        for (int off = 32; off > 0; off >>= 1) acc[q] += __shfl_down(acc[q], off);
    __shared__ float sh[4][32];
    if (lane == 0) {
#pragma unroll
        for (int q = 0; q < 32; ++q) sh[wv][q] = acc[q];
    }
    __syncthreads();
    if (tid < 32)
        part[blockIdx.x * 32 + tid] = sh[0][tid] + sh[1][tid] + sh[2][tid] + sh[3][tid];
}

// single block: image path, sum partials, a00 = colsum/N + b2[0], concat, log_softmax
__global__ void k6_final(const float* __restrict__ x, const float* __restrict__ vocab,
                         const float* __restrict__ W_lin1, const float* __restrict__ w2,
                         const float* __restrict__ w3, const float* __restrict__ W4,
                         const float* __restrict__ b2, const float* __restrict__ part,
                         float* __restrict__ out) {
    __shared__ float sh[256];
    __shared__ float hvec[70];
    int tid = threadIdx.x;
    int r = tid >> 3, sub = tid & 7;
    float pt = 0.f;
    if (r < 30) {
        for (int k = sub; k < 512; k += 8) pt += W_lin1[r*512 + k] * x[k];
    }
    sh[tid] = pt;
    __syncthreads();
    if (tid < 30) {
        float hi = 0.f;
        for (int i = 0; i < 8; ++i) hi += sh[tid*8 + i];
        float acc = 0.f;
        for (int k = 0; k < 64; ++k) acc += w3[k] / (1.f + __expf(-w2[k] * hi));
        hvec[30 + tid] = 1.f / (1.f + __expf(-acc));
        float cs = 0.f;
        for (int b = 0; b < NPART; ++b) cs += part[b*32 + tid];
        hvec[tid] = cs * (1.0f / (float)NN) + b2[tid];
    }
    if (tid >= 64 && tid < 74) hvec[60 + (tid - 64)] = vocab[tid - 64];
    __syncthreads();
    if (tid == 0) {
        float p0 = 0.f, p1 = 0.f;
        for (int k = 0; k < 70; ++k) {
            p0 += W4[k] * hvec[k];
            p1 += W4[70 + k] * hvec[k];
        }
        float mx = fmaxf(p0, p1);
        float l = logf(__expf(p0 - mx) + __expf(p1 - mx));
        out[0] = p0 - mx - l;
        out[1] = p1 - mx - l;
    }
}

extern "C" void kernel_launch(void* const* d_in, const int* in_sizes, int n_in,
                              void* d_out, int out_size, void* d_ws, size_t ws_size,
                              hipStream_t stream) {
    const float* x      = (const float*)d_in[0];
    const float* feat   = (const float*)d_in[1];
    const float* vocab  = (const float*)d_in[2];
    const int*   src    = (const int*)d_in[3];
    const int*   dst    = (const int*)d_in[4];
    const float* W_lin1 = (const float*)d_in[5];
    const float* w_c2   = (const float*)d_in[6];
    const float* w_c3   = (const float*)d_in[7];
    const float* W_lin4 = (const float*)d_in[8];
    const float* W1     = (const float*)d_in[9];
    const float* al1    = (const float*)d_in[10];
    const float* ar1    = (const float*)d_in[11];
    const float* b1     = (const float*)d_in[12];
    const float* W2     = (const float*)d_in[13];
    const float* al2    = (const float*)d_in[14];
    const float* ar2    = (const float*)d_in[15];
    const float* b2     = (const float*)d_in[16];
    float* out = (float*)d_out;
    float* w = (float*)d_ws;

    unsigned* counts  = (unsigned*)(w + OFF_COUNTS);
    unsigned* offsets = (unsigned*)(w + OFF_OFFSETS);
    unsigned* bsum    = (unsigned*)(w + OFF_BSUM);
    unsigned* boff    = (unsigned*)(w + OFF_BOFF);
    float*    clcr    = w + OFF_CLCR;
    float*    er1     = w + OFF_ER1;
    float*    er2     = w + OFF_ER2;
    unsigned* rank    = (unsigned*)(w + OFF_RANK);
    float4*   pfeat   = (float4*)(w + OFF_PFEAT);
    unsigned* bsrc    = (unsigned*)(w + OFF_BSRC);
    __half*   z2h     = (__half*)(w + OFF_Z2H);
    float*    part    = w + OFF_PARTS;

    k0_prep<<<NPART, 256, 0, stream>>>(counts, W1, al1, ar1, clcr);
    k1_hist_pack<<<(NE + 255) / 256, 256, 0, stream>>>(dst, counts, rank, feat, clcr, pfeat, er1);
    kS1<<<NPART, 256, 0, stream>>>(counts, bsum);
    kS2<<<1, 512, 0, stream>>>(bsum, boff);
    kS3<<<NPART, 256, 0, stream>>>(counts, boff, offsets);
    k3_scatter<<<(NE + 255) / 256, 256, 0, stream>>>(src, dst, offsets, rank, bsrc);
    k4_node<<<NPART, 256, 0, stream>>>(offsets, bsrc, pfeat, er1, W1, b1, W2, al2, ar2, z2h, er2);
    k5_layer2<<<NPART, 256, 0, stream>>>(offsets, bsrc, z2h, er2, part);
    k6_final<<<1, 256, 0, stream>>>(x, vocab, W_lin1, w_c2, w_c3, W_lin4, b2, part, out);
}

// Round 6
// 234.234 us; speedup vs baseline: 2.3177x; 1.0836x over previous
//
#include <hip/hip_runtime.h>
#include <hip/hip_bf16.h>
#include <hip/hip_fp16.h>

#define NN 100000      // nodes
#define NE 1000000     // edges
#define NPART 391      // ceil(NN/256)

// ---------------- workspace layout (4-byte units) ----------------
#define OFF_COUNTS   0              // u32[NN]   (zeroed by k0)
#define OFF_OFFSETS  100000         // u32[NN+1]
#define OFF_BSUM     200004         // u32[NPART]
#define OFF_BOFF     200396         // u32[NPART]
#define OFF_CLCR     200788         // f32[8]
#define OFF_ER1      200796         // f32[NN]
#define OFF_ER2      300796         // f32[NN]
#define OFF_RANK     400796         // u32[NE]
#define OFF_PFEAT    1400796        // float4[NN]  {f0,f1,f2,el1}  (16B aligned)
#define OFF_BSRC     1800796        // u32[NE]
#define OFF_Z2H      2800796        // half[32*NN] (64B rows; [30]=el2, [31]=0)
#define OFF_PARTS    4400796        // f32[NPART*32]

#define PK2(a,b) __builtin_bit_cast(float, __floats2half2_rn((a),(b)))

// zero hist counts + compute cl[k]=W1[k,:64]@al1, cr[k]=W1[k,:64]@ar1
__global__ void k0_prep(unsigned* __restrict__ counts, const float* __restrict__ W1,
                        const float* __restrict__ al1, const float* __restrict__ ar1,
                        float* __restrict__ clcr) {
    int i = blockIdx.x * blockDim.x + threadIdx.x;
    if (i < NN) counts[i] = 0u;
    if (blockIdx.x == 0 && threadIdx.x < 64) {
        int j = threadIdx.x;
        float a = al1[j], r = ar1[j];
#pragma unroll
        for (int k = 0; k < 3; ++k) {
            float wv = W1[k*128 + j];
            float vl = wv * a, vr = wv * r;
            for (int off = 32; off > 0; off >>= 1) {
                vl += __shfl_down(vl, off);
                vr += __shfl_down(vr, off);
            }
            if (j == 0) { clcr[k] = vl; clcr[4 + k] = vr; }
        }
    }
}

// histogram of dst (rank = stable per-node slot); low blocks also pack pfeat/er1
__global__ void k1_hist_pack(const int* __restrict__ dst, unsigned* __restrict__ counts,
                             unsigned* __restrict__ rank, const float* __restrict__ feat,
                             const float* __restrict__ clcr, float4* __restrict__ pfeat,
                             float* __restrict__ er1) {
    int e = blockIdx.x * blockDim.x + threadIdx.x;
    if (e < NE) rank[e] = atomicAdd(counts + dst[e], 1u);
    int n = e;
    if (n < NN) {
        float f0 = feat[n*3], f1 = feat[n*3+1], f2 = feat[n*3+2];
        float el = f0*clcr[0] + f1*clcr[1] + f2*clcr[2];
        float er = f0*clcr[4] + f1*clcr[5] + f2*clcr[6];
        pfeat[n] = make_float4(f0, f1, f2, el);
        er1[n] = er;
    }
}

// scan phase 1: per-block sum of counts
__global__ void kS1(const unsigned* __restrict__ counts, unsigned* __restrict__ bsum) {
    __shared__ unsigned sh[256];
    int t = threadIdx.x;
    int i = blockIdx.x * 256 + t;
    sh[t] = (i < NN) ? counts[i] : 0u;
    __syncthreads();
    for (int off = 128; off > 0; off >>= 1) {
        if (t < off) sh[t] += sh[t + off];
        __syncthreads();
    }
    if (t == 0) bsum[blockIdx.x] = sh[0];
}

// scan phase 2: single-block exclusive scan of the NPART block sums
__global__ void kS2(const unsigned* __restrict__ bsum, unsigned* __restrict__ boff) {
    __shared__ unsigned sh[512];
    int t = threadIdx.x;
    unsigned v = (t < NPART) ? bsum[t] : 0u;
    sh[t] = v;
    __syncthreads();
    for (int off = 1; off < 512; off <<= 1) {
        unsigned u = (t >= off) ? sh[t - off] : 0u;
        __syncthreads();
        sh[t] += u;
        __syncthreads();
    }
    if (t < NPART) boff[t] = sh[t] - v;   // exclusive
}

// scan phase 3: intra-block exclusive scan + block offset -> offsets[]
__global__ void kS3(const unsigned* __restrict__ counts, const unsigned* __restrict__ boff,
                    unsigned* __restrict__ offsets) {
    __shared__ unsigned sh[256];
    int t = threadIdx.x;
    int i = blockIdx.x * 256 + t;
    unsigned v = (i < NN) ? counts[i] : 0u;
    sh[t] = v;
    __syncthreads();
    for (int off = 1; off < 256; off <<= 1) {
        unsigned u = (t >= off) ? sh[t - off] : 0u;
        __syncthreads();
        sh[t] += u;
        __syncthreads();
    }
    if (i < NN) offsets[i] = boff[blockIdx.x] + sh[t] - v;
    if (i == NN - 1) offsets[NN] = NE;
}

// per edge: slot = offsets[d] + rank[e]; write only the src index (4 B scatter)
__global__ void k3_scatter(const int* __restrict__ src, const int* __restrict__ dst,
                           const unsigned* __restrict__ offsets, const unsigned* __restrict__ rank,
                           unsigned* __restrict__ bsrc) {
    int e = blockIdx.x * blockDim.x + threadIdx.x;
    if (e >= NE) return;
    bsrc[offsets[dst[e]] + rank[e]] = (unsigned)src[e];
}

// per node: gather pfeat[src], recompute p, aggregate; then z2 row via 30 register
// accumulators (NO 64-elem private array -> no LDS demotion), fp16 pack, er2
__global__ void k4_node(const unsigned* __restrict__ offsets, const unsigned* __restrict__ bsrc,
                        const float4* __restrict__ pfeat, const float* __restrict__ er1,
                        const float* __restrict__ W1, const float* __restrict__ b1,
                        const float* __restrict__ W2, const float* __restrict__ al2,
                        const float* __restrict__ ar2,
                        __half* __restrict__ z2h, float* __restrict__ er2) {
    __shared__ float sW1[192], sb1[64], sW2[1920], sal2[30], sar2[30];
    int tid = threadIdx.x;
    for (int i = tid; i < 192; i += 256) sW1[i] = W1[(i >> 6)*128 + (i & 63)];
    for (int i = tid; i < 1920; i += 256) sW2[i] = W2[(i / 30)*60 + (i % 30)];
    if (tid < 64) sb1[tid] = b1[tid];
    if (tid < 30) { sal2[tid] = al2[tid]; sar2[tid] = ar2[tid]; }
    __syncthreads();
    int n = blockIdx.x * 256 + tid;
    if (n >= NN) return;
    unsigned beg = offsets[n], end = offsets[n + 1];
    float erd = er1[n];
    float s0 = 0.f, s1 = 0.f, s2 = 0.f, sp = 0.f;
    for (unsigned i = beg; i < end; ++i) {
        unsigned s = bsrc[i];
        float4 v = pfeat[s];
        float ee = v.w + erd;
        ee = (ee >= 0.f) ? ee : 0.2f * ee;
        float p = __expf(ee);
        s0 += p * v.x; s1 += p * v.y; s2 += p * v.z; sp += p;
    }
    float inv = (sp > 0.f) ? 1.f / sp : 0.f;
    float a0 = s0 * inv, a1 = s1 * inv, a2 = s2 * inv;
    float z[30];
#pragma unroll
    for (int c = 0; c < 30; ++c) z[c] = 0.f;
    for (int j = 0; j < 64; ++j) {
        float rj = fmaxf(a0*sW1[j] + a1*sW1[64 + j] + a2*sW1[128 + j] + sb1[j], 0.f);
#pragma unroll
        for (int c = 0; c < 30; ++c) z[c] += rj * sW2[j*30 + c];
    }
    float sl = 0.f, sr = 0.f;
#pragma unroll
    for (int c = 0; c < 30; ++c) { sl += z[c] * sal2[c]; sr += z[c] * sar2[c]; }
    float4* outp = (float4*)(z2h + (size_t)n * 32);
    outp[0] = make_float4(PK2(z[0],z[1]),  PK2(z[2],z[3]),  PK2(z[4],z[5]),  PK2(z[6],z[7]));
    outp[1] = make_float4(PK2(z[8],z[9]),  PK2(z[10],z[11]),PK2(z[12],z[13]),PK2(z[14],z[15]));
    outp[2] = make_float4(PK2(z[16],z[17]),PK2(z[18],z[19]),PK2(z[20],z[21]),PK2(z[22],z[23]));
    outp[3] = make_float4(PK2(z[24],z[25]),PK2(z[26],z[27]),PK2(z[28],z[29]),PK2(sl, 0.f));
    er2[n] = sr;
}

// per node: gather fp16 z2 rows (64 B, el2 included), softmax-weighted colsum partials
__global__ void k5_layer2(const unsigned* __restrict__ offsets, const unsigned* __restrict__ bsrc,
                          const __half* __restrict__ z2h, const float* __restrict__ er2,
                          float* __restrict__ part) {
    int tid = threadIdx.x;
    int lane = tid & 63, wv = tid >> 6;
    int n = blockIdx.x * 256 + tid;
    float acc[32];
#pragma unroll
    for (int q = 0; q < 32; ++q) acc[q] = 0.f;
    if (n < NN) {
        unsigned beg = offsets[n], end = offsets[n + 1];
        float erd = er2[n];
        float sp = 0.f;
        for (unsigned i = beg; i < end; ++i) {
            unsigned s = bsrc[i];
            const float4* zr = (const float4*)(z2h + (size_t)s * 32);
            float4 r0 = zr[0], r1 = zr[1], r2 = zr[2], r3 = zr[3];
            float el = __half2float(__low2half(__builtin_bit_cast(__half2, r3.w)));
            float ee = el + erd;
            ee = (ee >= 0.f) ? ee : 0.2f * ee;
            float p = __expf(ee);
            sp += p;
#define ACC2(word, base) { float2 f = __half22float2(__builtin_bit_cast(__half2,(word))); \
                           acc[(base)] += p * f.x; acc[(base)+1] += p * f.y; }
            ACC2(r0.x, 0)  ACC2(r0.y, 2)  ACC2(r0.z, 4)  ACC2(r0.w, 6)
            ACC2(r1.x, 8)  ACC2(r1.y,10)  ACC2(r1.z,12)  ACC2(r1.w,14)
            ACC2(r2.x,16)  ACC2(r2.y,18)  ACC2(r2.z,20)  ACC2(r2.w,22)
            ACC2(r3.x,24)  ACC2(r3.y,26)  ACC2(r3.z,28)  ACC2(r3.w,30)
#undef ACC2
        }
        float inv = (sp > 0.f) ? 1.f / sp : 0.f;
#pragma unroll
        for (int q = 0; q < 32; ++q) acc[q] *= inv;
    }
#pragma unroll
    for (int q = 0; q < 32; ++q)
        for (int off = 32; off > 0; off >>= 1) acc[q] += __shfl_down(acc[q], off);
    __shared__ float sh[4][32];
    if (lane == 0) {
#pragma unroll
        for (int q = 0; q < 32; ++q) sh[wv][q] = acc[q];
    }
    __syncthreads();
    if (tid < 32)
        part[blockIdx.x * 32 + tid] = sh[0][tid] + sh[1][tid] + sh[2][tid] + sh[3][tid];
}

// single block: image path, sum partials, a00 = colsum/N + b2[0], concat, log_softmax
__global__ void k6_final(const float* __restrict__ x, const float* __restrict__ vocab,
                         const float* __restrict__ W_lin1, const float* __restrict__ w2,
                         const float* __restrict__ w3, const float* __restrict__ W4,
                         const float* __restrict__ b2, const float* __restrict__ part,
                         float* __restrict__ out) {
    __shared__ float sh[256];
    __shared__ float hvec[70];
    int tid = threadIdx.x;
    int r = tid >> 3, sub = tid & 7;
    float pt = 0.f;
    if (r < 30) {
        for (int k = sub; k < 512; k += 8) pt += W_lin1[r*512 + k] * x[k];
    }
    sh[tid] = pt;
    __syncthreads();
    if (tid < 30) {
        float hi = 0.f;
        for (int i = 0; i < 8; ++i) hi += sh[tid*8 + i];
        float acc = 0.f;
        for (int k = 0; k < 64; ++k) acc += w3[k] / (1.f + __expf(-w2[k] * hi));
        hvec[30 + tid] = 1.f / (1.f + __expf(-acc));
        float cs = 0.f;
        for (int b = 0; b < NPART; ++b) cs += part[b*32 + tid];
        hvec[tid] = cs * (1.0f / (float)NN) + b2[tid];
    }
    if (tid >= 64 && tid < 74) hvec[60 + (tid - 64)] = vocab[tid - 64];
    __syncthreads();
    if (tid == 0) {
        float p0 = 0.f, p1 = 0.f;
        for (int k = 0; k < 70; ++k) {
            p0 += W4[k] * hvec[k];
            p1 += W4[70 + k] * hvec[k];
        }
        float mx = fmaxf(p0, p1);
        float l = logf(__expf(p0 - mx) + __expf(p1 - mx));
        out[0] = p0 - mx - l;
        out[1] = p1 - mx - l;
    }
}

extern "C" void kernel_launch(void* const* d_in, const int* in_sizes, int n_in,
                              void* d_out, int out_size, void* d_ws, size_t ws_size,
                              hipStream_t stream) {
    const float* x      = (const float*)d_in[0];
    const float* feat   = (const float*)d_in[1];
    const float* vocab  = (const float*)d_in[2];
    const int*   src    = (const int*)d_in[3];
    const int*   dst    = (const int*)d_in[4];
    const float* W_lin1 = (const float*)d_in[5];
    const float* w_c2   = (const float*)d_in[6];
    const float* w_c3   = (const float*)d_in[7];
    const float* W_lin4 = (const float*)d_in[8];
    const float* W1     = (const float*)d_in[9];
    const float* al1    = (const float*)d_in[10];
    const float* ar1    = (const float*)d_in[11];
    const float* b1     = (const float*)d_in[12];
    const float* W2     = (const float*)d_in[13];
    const float* al2    = (const float*)d_in[14];
    const float* ar2    = (const float*)d_in[15];
    const float* b2     = (const float*)d_in[16];
    float* out = (float*)d_out;
    float* w = (float*)d_ws;

    unsigned* counts  = (unsigned*)(w + OFF_COUNTS);
    unsigned* offsets = (unsigned*)(w + OFF_OFFSETS);
    unsigned* bsum    = (unsigned*)(w + OFF_BSUM);
    unsigned* boff    = (unsigned*)(w + OFF_BOFF);
    float*    clcr    = w + OFF_CLCR;
    float*    er1     = w + OFF_ER1;
    float*    er2     = w + OFF_ER2;
    unsigned* rank    = (unsigned*)(w + OFF_RANK);
    float4*   pfeat   = (float4*)(w + OFF_PFEAT);
    unsigned* bsrc    = (unsigned*)(w + OFF_BSRC);
    __half*   z2h     = (__half*)(w + OFF_Z2H);
    float*    part    = w + OFF_PARTS;

    k0_prep<<<NPART, 256, 0, stream>>>(counts, W1, al1, ar1, clcr);
    k1_hist_pack<<<(NE + 255) / 256, 256, 0, stream>>>(dst, counts, rank, feat, clcr, pfeat, er1);
    kS1<<<NPART, 256, 0, stream>>>(counts, bsum);
    kS2<<<1, 512, 0, stream>>>(bsum, boff);
    kS3<<<NPART, 256, 0, stream>>>(counts, boff, offsets);
    k3_scatter<<<(NE + 255) / 256, 256, 0, stream>>>(src, dst, offsets, rank, bsrc);
    k4_node<<<NPART, 256, 0, stream>>>(offsets, bsrc, pfeat, er1, W1, b1, W2, al2, ar2, z2h, er2);
    k5_layer2<<<NPART, 256, 0, stream>>>(offsets, bsrc, z2h, er2, part);
    k6_final<<<1, 256, 0, stream>>>(x, vocab, W_lin1, w_c2, w_c3, W_lin4, b2, part, out);
}